// Round 3
// baseline (11420.724 us; speedup 1.0000x reference)
//
#include <hip/hip_runtime.h>
#include <hip/hip_bf16.h>

// ---------- types ----------
typedef __attribute__((ext_vector_type(8))) short  s16x8;
typedef __attribute__((ext_vector_type(4))) float  f32x4;
typedef __attribute__((ext_vector_type(4))) unsigned short u16x4;
typedef __attribute__((ext_vector_type(2))) unsigned long long u64x2;

#define B_  64
#define T_  1024
#define I_  512
#define H_  1024
#define O_  512
#define MT_ 65536   // B_*T_

// scan decomposition: 4 row-groups x 16 col-slices
#define RG_   4
#define CS_   16
#define WSLD  1048   // LDS row stride (shorts)

// ---------- helpers ----------
__device__ __forceinline__ unsigned short f2bf(float f) {
    unsigned u = __builtin_bit_cast(unsigned, f);
    u += 0x7FFFu + ((u >> 16) & 1u);
    return (unsigned short)(u >> 16);
}
__device__ __forceinline__ float bf2f(unsigned short h) {
    return __builtin_bit_cast(float, ((unsigned)h) << 16);
}
__device__ __forceinline__ void store_out(float* p, float v) { *p = v; }
__device__ __forceinline__ void store_out(unsigned short* p, float v) { *p = f2bf(v); }
__device__ __forceinline__ float to_f32(float v) { return v; }
__device__ __forceinline__ float to_f32(unsigned short v) { return bf2f(v); }

#define GL2LDS16(gp, lp) __builtin_amdgcn_global_load_lds( \
    (const __attribute__((address_space(1))) void*)(gp),   \
    (__attribute__((address_space(3))) void*)(lp), 16, 0, 0)

// ---------- conversion kernels ----------
__global__ void cvt_x(const float* __restrict__ src, unsigned short* __restrict__ dst, int n) {
    int stride = gridDim.x * blockDim.x * 4;
    for (int i = (blockIdx.x * blockDim.x + threadIdx.x) * 4; i < n; i += stride) {
        const float4 v = *(const float4*)(src + i);
        u16x4 o;
        o.x = f2bf(v.x); o.y = f2bf(v.y); o.z = f2bf(v.z); o.w = f2bf(v.w);
        *(u16x4*)(dst + i) = o;
    }
}

// dst[c][r] = bf16(src[row_off + r][c]);  src region [SR,SC] row-major -> dst [SC,SR]
__global__ void cvt_t(const float* __restrict__ src, unsigned short* __restrict__ dst,
                      int SR, int SC, int row_off) {
    __shared__ unsigned short tile[32][33];
    int c0 = blockIdx.x * 32, r0 = blockIdx.y * 32;
    int tx = threadIdx.x, ty = threadIdx.y;
    #pragma unroll
    for (int i = 0; i < 32; i += 8)
        tile[ty + i][tx] = f2bf(src[(size_t)(row_off + r0 + ty + i) * SC + c0 + tx]);
    __syncthreads();
    #pragma unroll
    for (int i = 0; i < 32; i += 8)
        dst[(size_t)(c0 + ty + i) * SR + r0 + tx] = tile[tx][ty + i];
}

// ---------- generic bf16 MFMA GEMM: C[M,N] = act(A[M,K] @ BT[N,K]^T + bias) ----------
template<typename OutT, bool LRELU, bool SCATTER>
__global__ __launch_bounds__(256)
void gemm_bf16(const unsigned short* __restrict__ A,
               const unsigned short* __restrict__ BT,
               const float* __restrict__ bias,
               OutT* __restrict__ C, int M, int K, int N)
{
    __shared__ unsigned short As[4096]; // [128][32]
    __shared__ unsigned short Bs[4096]; // [128][32]
    const int tid = threadIdx.x, lane = tid & 63, wid = tid >> 6;
    const int wr = wid >> 1, wc = wid & 1;
    const int m0 = blockIdx.x * 128, n0 = blockIdx.y * 128;

    f32x4 acc[4][4] = {};

    const int c = wid * 2;
    const int srow = lane >> 2;
    const int scol = (lane & 3) * 8;
    const unsigned short* Ag0 = A  + (size_t)(m0 + c * 16 + srow) * K + scol;
    const unsigned short* Ag1 = A  + (size_t)(m0 + c * 16 + 16 + srow) * K + scol;
    const unsigned short* Bg0 = BT + (size_t)(n0 + c * 16 + srow) * K + scol;
    const unsigned short* Bg1 = BT + (size_t)(n0 + c * 16 + 16 + srow) * K + scol;

    for (int k0 = 0; k0 < K; k0 += 32) {
        __syncthreads();
        GL2LDS16(Ag0 + k0, As + c * 512);
        GL2LDS16(Ag1 + k0, As + (c + 1) * 512);
        GL2LDS16(Bg0 + k0, Bs + c * 512);
        GL2LDS16(Bg1 + k0, Bs + (c + 1) * 512);
        __syncthreads();

        s16x8 af[4], bfr[4];
        #pragma unroll
        for (int i = 0; i < 4; i++)
            af[i] = *(const s16x8*)(As + (wr * 64 + i * 16 + (lane & 15)) * 32 + (lane >> 4) * 8);
        #pragma unroll
        for (int j = 0; j < 4; j++)
            bfr[j] = *(const s16x8*)(Bs + (wc * 64 + j * 16 + (lane & 15)) * 32 + (lane >> 4) * 8);
        #pragma unroll
        for (int i = 0; i < 4; i++)
            #pragma unroll
            for (int j = 0; j < 4; j++)
                acc[i][j] = __builtin_amdgcn_mfma_f32_16x16x32_bf16(af[i], bfr[j], acc[i][j], 0, 0, 0);
    }

    #pragma unroll
    for (int j = 0; j < 4; j++) {
        const int n = n0 + wc * 64 + j * 16 + (lane & 15);
        const float bv = bias[n];
        #pragma unroll
        for (int i = 0; i < 4; i++) {
            #pragma unroll
            for (int r = 0; r < 4; r++) {
                const int m = m0 + wr * 64 + i * 16 + (lane >> 4) * 4 + r;
                if (m < M) {
                    float v = acc[i][j][r] + bv;
                    if (LRELU) v = v >= 0.f ? v : 0.01f * v;
                    size_t row = SCATTER ? (size_t)((m & (T_ - 1)) * B_ + (m >> 10)) : (size_t)m;
                    store_out(&C[row * N + n], v);
                }
            }
        }
    }
}

// ---------- scan kernel v3: fence-free, barrier-free dataflow ----------
// 64 blocks (4 row-groups x 16 col-slices) x 256 thr, 1 block/CU (LDS-bound).
// All h/flag traffic via relaxed agent-scope atomics (cache-bypassing, L3-coherent).
// Per-WAVE flags: flags[rg*64 + slice*4 + wave] = steps completed. No __syncthreads
// in the t-loop; ordering: stores -> s_waitcnt vmcnt(0) -> flag store. Consumer:
// 64-lane ballot poll (one L3 round trip sees all 64 producer-wave flags).
template<typename PreT>
__global__ __launch_bounds__(256, 1)
void rnn_scan3(const unsigned short* __restrict__ WbotT,
               const PreT* __restrict__ pre,      // [T][B][H] t-major
               unsigned short* __restrict__ hbuf, // [2][B][H] bf16
               unsigned* __restrict__ flags)      // [RG_][64] u32
{
    __shared__ unsigned short Ws[64 * WSLD];
    const int tid = threadIdx.x, lane = tid & 63, w = tid >> 6;
    const int rg = (int)blockIdx.x >> 4;
    const int cs = (int)blockIdx.x & 15;
    const int row0 = rg * 16;
    const int n0 = cs * 64;

    for (int idx = tid; idx < 64 * 128; idx += 256) {
        int r = idx >> 7, ck = (idx & 127) * 8;
        *(s16x8*)(Ws + r * WSLD + ck) = *(const s16x8*)(WbotT + (size_t)(n0 + r) * H_ + ck);
    }
    __syncthreads();

    const int l15 = lane & 15, l4 = lane >> 4;
    const int hrow = row0 + l15;              // h row this thread reads AND writes
    const int col0 = n0 + w * 16 + l4 * 4;    // first of 4 consecutive output cols
    const unsigned short* wsbase = Ws + (size_t)(w * 16 + l15) * WSLD + l4 * 8;
    const unsigned* fp = flags + rg * 64 + lane;      // poll: lane = slice*4+wave
    unsigned* myflag = flags + rg * 64 + cs * 4 + w;  // publish

    float pv[4];
    #pragma unroll
    for (int r = 0; r < 4; r++)
        pv[r] = to_f32(pre[(size_t)hrow * H_ + col0 + r]);

    for (int t = 0; t < T_; ++t) {
        const unsigned short* hc = hbuf + ((t & 1) << 16);
        unsigned short*       hn = hbuf + (((t + 1) & 1) << 16);

        // issue next-step pre prefetch early (plain cached loads, overlap everything)
        float pvn[4];
        const int tn = (t + 1 < T_) ? t + 1 : t;
        #pragma unroll
        for (int r = 0; r < 4; r++)
            pvn[r] = to_f32(pre[((size_t)tn * B_ + hrow) * H_ + col0 + r]);

        // wait until every producer wave published step t (h_t complete at L3)
        if (t) {
            for (;;) {
                unsigned f = __hip_atomic_load(fp, __ATOMIC_RELAXED, __HIP_MEMORY_SCOPE_AGENT);
                if (__all((int)(f >= (unsigned)t))) break;
            }
            asm volatile("" ::: "memory");  // keep h loads below the poll
        }

        // issue ALL h loads back-to-back: 16 slices x 4 u64 (one L3 latency, amortized)
        const unsigned long long* hq =
            (const unsigned long long*)hc + (size_t)hrow * (H_ / 4) + l4 * 2;
        unsigned long long hv[16][4];
        #pragma unroll
        for (int i = 0; i < 16; ++i) {
            const unsigned long long* hp = hq + i * 16;
            hv[i][0] = __hip_atomic_load(hp + 0, __ATOMIC_RELAXED, __HIP_MEMORY_SCOPE_AGENT);
            hv[i][1] = __hip_atomic_load(hp + 1, __ATOMIC_RELAXED, __HIP_MEMORY_SCOPE_AGENT);
            hv[i][2] = __hip_atomic_load(hp + 8, __ATOMIC_RELAXED, __HIP_MEMORY_SCOPE_AGENT);
            hv[i][3] = __hip_atomic_load(hp + 9, __ATOMIC_RELAXED, __HIP_MEMORY_SCOPE_AGENT);
        }

        // mfma(Ws_frag, h_frag): C[ws_row][h_row] -> thread holds 4 consecutive
        // output cols (w*16+l4*4+r) of one h row (row0+l15)
        f32x4 a0 = {}, a1 = {};
        #pragma unroll
        for (int i = 0; i < 16; ++i) {
            u64x2 q0 = {hv[i][0], hv[i][1]};
            u64x2 q1 = {hv[i][2], hv[i][3]};
            s16x8 bf0 = __builtin_bit_cast(s16x8, q0);
            s16x8 bf1 = __builtin_bit_cast(s16x8, q1);
            s16x8 g0 = *(const s16x8*)(wsbase + i * 64);
            s16x8 g1 = *(const s16x8*)(wsbase + i * 64 + 32);
            a0 = __builtin_amdgcn_mfma_f32_16x16x32_bf16(g0, bf0, a0, 0, 0, 0);
            a1 = __builtin_amdgcn_mfma_f32_16x16x32_bf16(g1, bf1, a1, 0, 0, 0);
        }
        f32x4 acc = a0 + a1;

        u16x4 o;
        #pragma unroll
        for (int r = 0; r < 4; r++) {
            float v = acc[r] + pv[r];
            v = v >= 0.f ? v : 0.01f * v;
            o[r] = f2bf(v);
        }
        __hip_atomic_store((unsigned long long*)(hn + (size_t)hrow * H_ + col0),
                           __builtin_bit_cast(unsigned long long, o),
                           __ATOMIC_RELAXED, __HIP_MEMORY_SCOPE_AGENT);

        #pragma unroll
        for (int r = 0; r < 4; r++) pv[r] = pvn[r];

        // order: h stores acked at coherence point, THEN publish flag (relaxed)
        asm volatile("s_waitcnt vmcnt(0)" ::: "memory");
        if (lane == 0)
            __hip_atomic_store(myflag, (unsigned)(t + 1),
                               __ATOMIC_RELAXED, __HIP_MEMORY_SCOPE_AGENT);
    }
}

// ---------- launch ----------
extern "C" void kernel_launch(void* const* d_in, const int* in_sizes, int n_in,
                              void* d_out, int out_size, void* d_ws, size_t ws_size,
                              hipStream_t stream)
{
    const float* x     = (const float*)d_in[0];
    const float* W_in  = (const float*)d_in[1];
    const float* b_in  = (const float*)d_in[2];
    const float* W_h   = (const float*)d_in[3];
    const float* b_h   = (const float*)d_in[4];
    const float* W_out = (const float*)d_in[5];
    const float* b_out = (const float*)d_in[6];
    float* out = (float*)d_out;

    char* ws = (char*)d_ws;
    size_t off = 0;
    auto alloc = [&](size_t bytes) { void* p = ws + off; off += (bytes + 255) & ~(size_t)255; return p; };

    unsigned short* Xb    = (unsigned short*)alloc((size_t)MT_ * I_ * 2);
    unsigned short* WinT  = (unsigned short*)alloc((size_t)H_ * I_ * 2);
    unsigned short* WtopT = (unsigned short*)alloc((size_t)H_ * H_ * 2);
    unsigned short* WbotT = (unsigned short*)alloc((size_t)H_ * H_ * 2);
    unsigned short* WoutT = (unsigned short*)alloc((size_t)O_ * H_ * 2);
    unsigned short* Abuf  = (unsigned short*)alloc((size_t)MT_ * H_ * 2);
    unsigned short* hbuf  = (unsigned short*)alloc((size_t)2 * B_ * H_ * 2);
    unsigned*       flags = (unsigned*)alloc(RG_ * 64 * sizeof(unsigned));
    void* pre = ws + off;
    const bool pre_f32 = (off + (size_t)MT_ * H_ * 4) <= ws_size;

    hipMemsetAsync(hbuf, 0, (size_t)2 * B_ * H_ * 2, stream);
    hipMemsetAsync(flags, 0, RG_ * 64 * sizeof(unsigned), stream);

    cvt_x<<<2048, 256, 0, stream>>>(x, Xb, MT_ * I_);
    dim3 tb(32, 8);
    cvt_t<<<dim3(H_ / 32, I_ / 32), tb, 0, stream>>>(W_in,  WinT,  I_, H_, 0);
    cvt_t<<<dim3(H_ / 32, H_ / 32), tb, 0, stream>>>(W_h,   WtopT, H_, H_, 0);
    cvt_t<<<dim3(H_ / 32, H_ / 32), tb, 0, stream>>>(W_h,   WbotT, H_, H_, H_);
    cvt_t<<<dim3(O_ / 32, H_ / 32), tb, 0, stream>>>(W_out, WoutT, H_, O_, 0);

    // GEMM1: A = lrelu(X @ W_in + b_in)   [MT, H] bf16
    gemm_bf16<unsigned short, true, false>
        <<<dim3(MT_ / 128, H_ / 128), 256, 0, stream>>>(Xb, WinT, b_in, Abuf, MT_, I_, H_);

    // GEMM2: pre = A @ Wtop + b_h   written t-major [T][B][H]
    if (pre_f32) {
        gemm_bf16<float, false, true>
            <<<dim3(MT_ / 128, H_ / 128), 256, 0, stream>>>(Abuf, WtopT, b_h, (float*)pre, MT_, H_, H_);
        rnn_scan3<float><<<RG_ * CS_, 256, 0, stream>>>(WbotT, (const float*)pre, hbuf, flags);
    } else {
        gemm_bf16<unsigned short, false, true>
            <<<dim3(MT_ / 128, H_ / 128), 256, 0, stream>>>(Abuf, WtopT, b_h, (unsigned short*)pre, MT_, H_, H_);
        rnn_scan3<unsigned short><<<RG_ * CS_, 256, 0, stream>>>(WbotT, (const unsigned short*)pre, hbuf, flags);
    }

    // final: out = h_final @ W_out + b_out   (h_final = hbuf[0] since T even)
    gemm_bf16<float, false, false>
        <<<dim3(1, O_ / 128), 256, 0, stream>>>(hbuf, WoutT, b_out, out, B_, H_, O_);
}

// Round 4
// 7106.931 us; speedup vs baseline: 1.6070x; 1.6070x over previous
//
#include <hip/hip_runtime.h>
#include <hip/hip_bf16.h>

// ---------- types ----------
typedef __attribute__((ext_vector_type(8))) short  s16x8;
typedef __attribute__((ext_vector_type(4))) float  f32x4;
typedef __attribute__((ext_vector_type(4))) unsigned short u16x4;

#define B_  64
#define T_  1024
#define I_  512
#define H_  1024
#define O_  512
#define MT_ 65536   // B_*T_

// scan decomposition: 4 row-groups x 16 col-slices
#define RG_   4
#define CS_   16
#define WSLD  1048   // LDS row stride (shorts)

// ---------- helpers ----------
__device__ __forceinline__ unsigned short f2bf(float f) {
    unsigned u = __builtin_bit_cast(unsigned, f);
    u += 0x7FFFu + ((u >> 16) & 1u);
    return (unsigned short)(u >> 16);
}
__device__ __forceinline__ float bf2f(unsigned short h) {
    return __builtin_bit_cast(float, ((unsigned)h) << 16);
}
__device__ __forceinline__ void store_out(float* p, float v) { *p = v; }
__device__ __forceinline__ void store_out(unsigned short* p, float v) { *p = f2bf(v); }
__device__ __forceinline__ float to_f32(float v) { return v; }
__device__ __forceinline__ float to_f32(unsigned short v) { return bf2f(v); }

#define GL2LDS16(gp, lp) __builtin_amdgcn_global_load_lds( \
    (const __attribute__((address_space(1))) void*)(gp),   \
    (__attribute__((address_space(3))) void*)(lp), 16, 0, 0)

// ---------- conversion kernels ----------
__global__ void cvt_x(const float* __restrict__ src, unsigned short* __restrict__ dst, int n) {
    int stride = gridDim.x * blockDim.x * 4;
    for (int i = (blockIdx.x * blockDim.x + threadIdx.x) * 4; i < n; i += stride) {
        const float4 v = *(const float4*)(src + i);
        u16x4 o;
        o.x = f2bf(v.x); o.y = f2bf(v.y); o.z = f2bf(v.z); o.w = f2bf(v.w);
        *(u16x4*)(dst + i) = o;
    }
}

// dst[c][r] = bf16(src[row_off + r][c]);  src region [SR,SC] row-major -> dst [SC,SR]
__global__ void cvt_t(const float* __restrict__ src, unsigned short* __restrict__ dst,
                      int SR, int SC, int row_off) {
    __shared__ unsigned short tile[32][33];
    int c0 = blockIdx.x * 32, r0 = blockIdx.y * 32;
    int tx = threadIdx.x, ty = threadIdx.y;
    #pragma unroll
    for (int i = 0; i < 32; i += 8)
        tile[ty + i][tx] = f2bf(src[(size_t)(row_off + r0 + ty + i) * SC + c0 + tx]);
    __syncthreads();
    #pragma unroll
    for (int i = 0; i < 32; i += 8)
        dst[(size_t)(c0 + ty + i) * SR + r0 + tx] = tile[tx][ty + i];
}

// ---------- generic bf16 MFMA GEMM: C[M,N] = act(A[M,K] @ BT[N,K]^T + bias) ----------
template<typename OutT, bool LRELU, bool SCATTER>
__global__ __launch_bounds__(256)
void gemm_bf16(const unsigned short* __restrict__ A,
               const unsigned short* __restrict__ BT,
               const float* __restrict__ bias,
               OutT* __restrict__ C, int M, int K, int N)
{
    __shared__ unsigned short As[4096]; // [128][32]
    __shared__ unsigned short Bs[4096]; // [128][32]
    const int tid = threadIdx.x, lane = tid & 63, wid = tid >> 6;
    const int wr = wid >> 1, wc = wid & 1;
    const int m0 = blockIdx.x * 128, n0 = blockIdx.y * 128;

    f32x4 acc[4][4] = {};

    const int c = wid * 2;
    const int srow = lane >> 2;
    const int scol = (lane & 3) * 8;
    const unsigned short* Ag0 = A  + (size_t)(m0 + c * 16 + srow) * K + scol;
    const unsigned short* Ag1 = A  + (size_t)(m0 + c * 16 + 16 + srow) * K + scol;
    const unsigned short* Bg0 = BT + (size_t)(n0 + c * 16 + srow) * K + scol;
    const unsigned short* Bg1 = BT + (size_t)(n0 + c * 16 + 16 + srow) * K + scol;

    for (int k0 = 0; k0 < K; k0 += 32) {
        __syncthreads();
        GL2LDS16(Ag0 + k0, As + c * 512);
        GL2LDS16(Ag1 + k0, As + (c + 1) * 512);
        GL2LDS16(Bg0 + k0, Bs + c * 512);
        GL2LDS16(Bg1 + k0, Bs + (c + 1) * 512);
        __syncthreads();

        s16x8 af[4], bfr[4];
        #pragma unroll
        for (int i = 0; i < 4; i++)
            af[i] = *(const s16x8*)(As + (wr * 64 + i * 16 + (lane & 15)) * 32 + (lane >> 4) * 8);
        #pragma unroll
        for (int j = 0; j < 4; j++)
            bfr[j] = *(const s16x8*)(Bs + (wc * 64 + j * 16 + (lane & 15)) * 32 + (lane >> 4) * 8);
        #pragma unroll
        for (int i = 0; i < 4; i++)
            #pragma unroll
            for (int j = 0; j < 4; j++)
                acc[i][j] = __builtin_amdgcn_mfma_f32_16x16x32_bf16(af[i], bfr[j], acc[i][j], 0, 0, 0);
    }

    #pragma unroll
    for (int j = 0; j < 4; j++) {
        const int n = n0 + wc * 64 + j * 16 + (lane & 15);
        const float bv = bias[n];
        #pragma unroll
        for (int i = 0; i < 4; i++) {
            #pragma unroll
            for (int r = 0; r < 4; r++) {
                const int m = m0 + wr * 64 + i * 16 + (lane >> 4) * 4 + r;
                if (m < M) {
                    float v = acc[i][j][r] + bv;
                    if (LRELU) v = v >= 0.f ? v : 0.01f * v;
                    size_t row = SCATTER ? (size_t)((m & (T_ - 1)) * B_ + (m >> 10)) : (size_t)m;
                    store_out(&C[row * N + n], v);
                }
            }
        }
    }
}

// ---------- scan v4: dataflow with coalesced cache-bypass (sc0 sc1) vector ops ----------
// 64 blocks (4 row-groups x 16 col-slices) x 256 thr. Per-wave flags, no barriers in
// the t-loop. h exchange: global_load_dwordx4 / store_dwordx2 with sc0 sc1 (L1+L2
// bypass, coherent at L3, full TA coalescing). Order: h stores -> vmcnt(0) -> flag.
// h loads pipelined in 4 batches of 8 with counted vmcnt waits.

#define HL(d, OFFSTR) asm volatile( \
    "global_load_dwordx4 %0, %1, off offset:" OFFSTR " sc0 sc1" \
    : "=v"(d) : "v"(hbase))

#define WAITV(NSTR) do { \
    asm volatile("s_waitcnt vmcnt(" NSTR ")" ::: "memory"); \
    __builtin_amdgcn_sched_barrier(0); } while (0)

#define MFMA8(buf, base) do { \
    _Pragma("unroll") \
    for (int kk = 0; kk < 8; ++kk) { \
        s16x8 g = *(const s16x8*)(wsbase + (base + kk) * 32); \
        ac[kk & 3] = __builtin_amdgcn_mfma_f32_16x16x32_bf16(g, buf[kk], ac[kk & 3], 0, 0, 0); \
    } } while (0)

template<typename PreT>
__global__ __launch_bounds__(256, 1)
void rnn_scan4(const unsigned short* __restrict__ WbotT,
               const PreT* __restrict__ pre,      // [T][B][H] t-major
               unsigned short* __restrict__ hbuf, // [2][B][H] bf16
               unsigned* __restrict__ flags)      // [RG_][64] u32
{
    __shared__ unsigned short Ws[64 * WSLD];
    const int tid = threadIdx.x, lane = tid & 63, w = tid >> 6;
    const int rg = (int)blockIdx.x >> 4;
    const int cs = (int)blockIdx.x & 15;
    const int row0 = rg * 16, n0 = cs * 64;

    for (int idx = tid; idx < 64 * 128; idx += 256) {
        int r = idx >> 7, ck = (idx & 127) * 8;
        *(s16x8*)(Ws + r * WSLD + ck) = *(const s16x8*)(WbotT + (size_t)(n0 + r) * H_ + ck);
    }
    __syncthreads();

    const int l15 = lane & 15, l4 = lane >> 4;
    const int hrow = row0 + l15;              // h row this thread reads AND writes
    const int col0 = n0 + w * 16 + l4 * 4;    // 4 consecutive output cols
    const unsigned short* wsbase = Ws + (size_t)(w * 16 + l15) * WSLD + l4 * 8;
    const unsigned* fp = flags + rg * 64 + lane;      // poll: lane = slice*4+wave
    unsigned* myflag = flags + rg * 64 + cs * 4 + w;  // publish

    float pv[4];
    #pragma unroll
    for (int r = 0; r < 4; r++)
        pv[r] = to_f32(pre[(size_t)hrow * H_ + col0 + r]);

    for (int t = 0; t < T_; ++t) {
        const unsigned short* hc = hbuf + ((t & 1) << 16);
        unsigned short*       hn = hbuf + (((t + 1) & 1) << 16);

        // next-step pre prefetch (plain cached loads; drained by poll/batch waits)
        float pvn[4];
        const int tn = (t + 1 < T_) ? t + 1 : t;
        #pragma unroll
        for (int r = 0; r < 4; r++)
            pvn[r] = to_f32(pre[((size_t)tn * B_ + hrow) * H_ + col0 + r]);

        // wait for all 64 producer waves of this row-group to publish step t
        if (t) {
            unsigned f;
            do {
                asm volatile("global_load_dword %0, %1, off sc0 sc1\n\t"
                             "s_waitcnt vmcnt(0)"
                             : "=v"(f) : "v"(fp) : "memory");
            } while (!__all((int)(f >= (unsigned)t)));
        }

        // h row base for this thread: chunk i (i=0..31) lives at offset i*64 bytes
        const unsigned short* hbase = hc + (size_t)hrow * H_ + l4 * 8;

        s16x8 hA[8], hB[8];
        f32x4 ac[4] = {};

        HL(hA[0], "0");    HL(hA[1], "64");   HL(hA[2], "128");  HL(hA[3], "192");
        HL(hA[4], "256");  HL(hA[5], "320");  HL(hA[6], "384");  HL(hA[7], "448");
        HL(hB[0], "512");  HL(hB[1], "576");  HL(hB[2], "640");  HL(hB[3], "704");
        HL(hB[4], "768");  HL(hB[5], "832");  HL(hB[6], "896");  HL(hB[7], "960");

        WAITV("8");                 // chunks 0-7 ready
        MFMA8(hA, 0);
        HL(hA[0], "1024"); HL(hA[1], "1088"); HL(hA[2], "1152"); HL(hA[3], "1216");
        HL(hA[4], "1280"); HL(hA[5], "1344"); HL(hA[6], "1408"); HL(hA[7], "1472");
        WAITV("8");                 // chunks 8-15 ready
        MFMA8(hB, 8);
        HL(hB[0], "1536"); HL(hB[1], "1600"); HL(hB[2], "1664"); HL(hB[3], "1728");
        HL(hB[4], "1792"); HL(hB[5], "1856"); HL(hB[6], "1920"); HL(hB[7], "1984");
        WAITV("8");                 // chunks 16-23 ready
        MFMA8(hA, 16);
        WAITV("0");                 // chunks 24-31 ready
        MFMA8(hB, 24);

        f32x4 acc = (ac[0] + ac[1]) + (ac[2] + ac[3]);

        u16x4 o;
        #pragma unroll
        for (int r = 0; r < 4; r++) {
            float v = acc[r] + pv[r];
            v = v >= 0.f ? v : 0.01f * v;
            o[r] = f2bf(v);
        }
        {
            unsigned long long ov = __builtin_bit_cast(unsigned long long, o);
            unsigned short* sp = hn + (size_t)hrow * H_ + col0;
            asm volatile("global_store_dwordx2 %0, %1, off sc0 sc1"
                         :: "v"(sp), "v"(ov) : "memory");
        }

        #pragma unroll
        for (int r = 0; r < 4; r++) pv[r] = pvn[r];

        // h stores acked at coherence point, THEN publish
        asm volatile("s_waitcnt vmcnt(0)" ::: "memory");
        if (lane == 0) {
            unsigned tv = (unsigned)(t + 1);
            asm volatile("global_store_dword %0, %1, off sc0 sc1"
                         :: "v"(myflag), "v"(tv) : "memory");
        }
    }
}

// ---------- launch ----------
extern "C" void kernel_launch(void* const* d_in, const int* in_sizes, int n_in,
                              void* d_out, int out_size, void* d_ws, size_t ws_size,
                              hipStream_t stream)
{
    const float* x     = (const float*)d_in[0];
    const float* W_in  = (const float*)d_in[1];
    const float* b_in  = (const float*)d_in[2];
    const float* W_h   = (const float*)d_in[3];
    const float* b_h   = (const float*)d_in[4];
    const float* W_out = (const float*)d_in[5];
    const float* b_out = (const float*)d_in[6];
    float* out = (float*)d_out;

    char* ws = (char*)d_ws;
    size_t off = 0;
    auto alloc = [&](size_t bytes) { void* p = ws + off; off += (bytes + 255) & ~(size_t)255; return p; };

    unsigned short* Xb    = (unsigned short*)alloc((size_t)MT_ * I_ * 2);
    unsigned short* WinT  = (unsigned short*)alloc((size_t)H_ * I_ * 2);
    unsigned short* WtopT = (unsigned short*)alloc((size_t)H_ * H_ * 2);
    unsigned short* WbotT = (unsigned short*)alloc((size_t)H_ * H_ * 2);
    unsigned short* WoutT = (unsigned short*)alloc((size_t)O_ * H_ * 2);
    unsigned short* Abuf  = (unsigned short*)alloc((size_t)MT_ * H_ * 2);
    unsigned short* hbuf  = (unsigned short*)alloc((size_t)2 * B_ * H_ * 2);
    unsigned*       flags = (unsigned*)alloc(RG_ * 64 * sizeof(unsigned));
    void* pre = ws + off;
    const bool pre_f32 = (off + (size_t)MT_ * H_ * 4) <= ws_size;

    hipMemsetAsync(hbuf, 0, (size_t)2 * B_ * H_ * 2, stream);
    hipMemsetAsync(flags, 0, RG_ * 64 * sizeof(unsigned), stream);

    cvt_x<<<2048, 256, 0, stream>>>(x, Xb, MT_ * I_);
    dim3 tb(32, 8);
    cvt_t<<<dim3(H_ / 32, I_ / 32), tb, 0, stream>>>(W_in,  WinT,  I_, H_, 0);
    cvt_t<<<dim3(H_ / 32, H_ / 32), tb, 0, stream>>>(W_h,   WtopT, H_, H_, 0);
    cvt_t<<<dim3(H_ / 32, H_ / 32), tb, 0, stream>>>(W_h,   WbotT, H_, H_, H_);
    cvt_t<<<dim3(O_ / 32, H_ / 32), tb, 0, stream>>>(W_out, WoutT, H_, O_, 0);

    // GEMM1: A = lrelu(X @ W_in + b_in)   [MT, H] bf16
    gemm_bf16<unsigned short, true, false>
        <<<dim3(MT_ / 128, H_ / 128), 256, 0, stream>>>(Xb, WinT, b_in, Abuf, MT_, I_, H_);

    // GEMM2: pre = A @ Wtop + b_h   written t-major [T][B][H]
    if (pre_f32) {
        gemm_bf16<float, false, true>
            <<<dim3(MT_ / 128, H_ / 128), 256, 0, stream>>>(Abuf, WtopT, b_h, (float*)pre, MT_, H_, H_);
        rnn_scan4<float><<<RG_ * CS_, 256, 0, stream>>>(WbotT, (const float*)pre, hbuf, flags);
    } else {
        gemm_bf16<unsigned short, false, true>
            <<<dim3(MT_ / 128, H_ / 128), 256, 0, stream>>>(Abuf, WtopT, b_h, (unsigned short*)pre, MT_, H_, H_);
        rnn_scan4<unsigned short><<<RG_ * CS_, 256, 0, stream>>>(WbotT, (const unsigned short*)pre, hbuf, flags);
    }

    // final: out = h_final @ W_out + b_out   (h_final = hbuf[0] since T even)
    gemm_bf16<float, false, false>
        <<<dim3(1, O_ / 128), 256, 0, stream>>>(hbuf, WoutT, b_out, out, B_, H_, O_);
}